// Round 1
// baseline (254.385 us; speedup 1.0000x reference)
//
#include <hip/hip_runtime.h>
#include <hip/hip_bf16.h>

// Problem constants (from setup_inputs): x [B=4, C=256, W=64, H=64] fp32
#define BATCH 4
#define CDIM  256
#define NTOK  4096   // W*H

#define BM 128
#define BN 128
#define BK 32
#define LDA 40       // padded bf16 leading dim (40*2=80B, 16B-aligned rows, ~2-way conflicts)

typedef short  bf16x8  __attribute__((ext_vector_type(8)));
typedef float  floatx4 __attribute__((ext_vector_type(4)));
typedef unsigned int uintx4 __attribute__((ext_vector_type(4)));

__device__ inline unsigned f2bf1(float f) {
    unsigned u = __float_as_uint(f);
    u += 0x7fffu + ((u >> 16) & 1u);   // round-to-nearest-even
    return u >> 16;
}
__device__ inline unsigned f2bf2(float lo, float hi) {
    return f2bf1(lo) | (f2bf1(hi) << 16);
}

// Kernel 1: per-token L2 norms; also zero the rowsum accumulators.
__global__ __launch_bounds__(256) void norms_kernel(const float* __restrict__ x,
                                                    float* __restrict__ norms,
                                                    float* __restrict__ rowsum) {
    int g = blockIdx.x * 256 + threadIdx.x;        // 0 .. B*N-1 (grid = 64 blocks)
    int b = g >> 12;
    int t = g & (NTOK - 1);
    const float* p = x + (size_t)b * CDIM * NTOK + t;
    float s = 0.f;
#pragma unroll 8
    for (int c = 0; c < CDIM; ++c) {
        float v = p[(size_t)c * NTOK];
        s += v * v;
    }
    norms[g] = sqrtf(s);
    rowsum[g] = 0.f;
}

// Kernel 2: G = X^T X (per batch) via bf16 MFMA; epilogue applies
// 1/(ni*nj+1e-6), exp(s-1), stores unnormalized exp, atomically adds row sums.
__global__ __launch_bounds__(256) void gemm_exp_kernel(const float* __restrict__ x,
                                                       const float* __restrict__ norms,
                                                       float* __restrict__ out,
                                                       float* __restrict__ rowsum) {
    __shared__ short As[BM * LDA];
    __shared__ short Bs[BN * LDA];

    const int tid = threadIdx.x;
    const int b = blockIdx.z;
    const int rowBase = blockIdx.y * BM;
    const int colBase = blockIdx.x * BN;

    const int tt = tid & 127;            // token within tile (staging)
    const int kh = (tid >> 7) << 4;      // 0 or 16: channel half (staging)

    const int lane = tid & 63;
    const int wid  = tid >> 6;
    const int wr = (wid >> 1) << 6;      // wave row offset: 0 or 64
    const int wc = (wid & 1) << 6;       // wave col offset: 0 or 64
    const int r0 = lane & 15;
    const int kq = lane >> 4;            // 0..3

    floatx4 acc[4][4];
#pragma unroll
    for (int m = 0; m < 4; ++m)
#pragma unroll
        for (int n = 0; n < 4; ++n)
            acc[m][n] = (floatx4){0.f, 0.f, 0.f, 0.f};

    const size_t xb = (size_t)b * CDIM * NTOK;

    for (int kk = 0; kk < CDIM; kk += BK) {
        __syncthreads();
        // ---- stage A tile: tokens rowBase..+127, channels kk..kk+31, LDS [token][k]
        {
            const float* p = x + xb + (size_t)(kk + kh) * NTOK + rowBase + tt;
            unsigned w[8];
#pragma unroll
            for (int j = 0; j < 8; ++j) {
                float f0 = p[(size_t)(2 * j) * NTOK];
                float f1 = p[(size_t)(2 * j + 1) * NTOK];
                w[j] = f2bf2(f0, f1);
            }
            uintx4* dst = (uintx4*)&As[tt * LDA + kh];
            dst[0] = (uintx4){w[0], w[1], w[2], w[3]};
            dst[1] = (uintx4){w[4], w[5], w[6], w[7]};
        }
        // ---- stage B tile: tokens colBase..+127
        {
            const float* p = x + xb + (size_t)(kk + kh) * NTOK + colBase + tt;
            unsigned w[8];
#pragma unroll
            for (int j = 0; j < 8; ++j) {
                float f0 = p[(size_t)(2 * j) * NTOK];
                float f1 = p[(size_t)(2 * j + 1) * NTOK];
                w[j] = f2bf2(f0, f1);
            }
            uintx4* dst = (uintx4*)&Bs[tt * LDA + kh];
            dst[0] = (uintx4){w[0], w[1], w[2], w[3]};
            dst[1] = (uintx4){w[4], w[5], w[6], w[7]};
        }
        __syncthreads();

        // ---- fragments + MFMA
        bf16x8 af[4], bfc[4];
#pragma unroll
        for (int m = 0; m < 4; ++m)
            af[m] = *(const bf16x8*)&As[(wr + m * 16 + r0) * LDA + kq * 8];
#pragma unroll
        for (int n = 0; n < 4; ++n)
            bfc[n] = *(const bf16x8*)&Bs[(wc + n * 16 + r0) * LDA + kq * 8];
#pragma unroll
        for (int m = 0; m < 4; ++m)
#pragma unroll
            for (int n = 0; n < 4; ++n)
                acc[m][n] = __builtin_amdgcn_mfma_f32_16x16x32_bf16(af[m], bfc[n], acc[m][n], 0, 0, 0);
    }

    // ---- epilogue: normalize by norms, exp(s-1), store, row-sum reduce
    const size_t outBase = (size_t)b * NTOK * NTOK;
    const int nb = b * NTOK;
    float nj[4];
#pragma unroll
    for (int n = 0; n < 4; ++n)
        nj[n] = norms[nb + colBase + wc + n * 16 + r0];

#pragma unroll
    for (int m = 0; m < 4; ++m) {
#pragma unroll
        for (int r = 0; r < 4; ++r) {
            const int gi = rowBase + wr + m * 16 + kq * 4 + r;  // global row token
            const float ni = norms[nb + gi];
            float psum = 0.f;
#pragma unroll
            for (int n = 0; n < 4; ++n) {
                const int gj = colBase + wc + n * 16 + r0;       // global col token
                float e = acc[m][n][r];
                float s = e / (ni * nj[n] + 1e-6f);
                float pv = __expf(s - 1.0f);
                out[outBase + (size_t)gi * NTOK + gj] = pv;
                psum += pv;
            }
            // reduce over the 16 lanes (r0) that share this row
            psum += __shfl_xor(psum, 1);
            psum += __shfl_xor(psum, 2);
            psum += __shfl_xor(psum, 4);
            psum += __shfl_xor(psum, 8);
            if (r0 == 0) atomicAdd(&rowsum[nb + gi], psum);
        }
    }
}

// Kernel 3: out[row][*] *= 1/rowsum[row]
__global__ __launch_bounds__(256) void scale_kernel(float* __restrict__ out,
                                                    const float* __restrict__ rowsum) {
    const size_t total4 = (size_t)BATCH * NTOK * NTOK / 4;
    floatx4* o4 = (floatx4*)out;
    for (size_t idx = (size_t)blockIdx.x * 256 + threadIdx.x; idx < total4;
         idx += (size_t)gridDim.x * 256) {
        int row = (int)(idx >> 10);            // N/4 = 1024 float4 per row -> row = b*N+i
        float rinv = 1.0f / rowsum[row];
        floatx4 v = o4[idx];
        v[0] *= rinv; v[1] *= rinv; v[2] *= rinv; v[3] *= rinv;
        o4[idx] = v;
    }
}

extern "C" void kernel_launch(void* const* d_in, const int* in_sizes, int n_in,
                              void* d_out, int out_size, void* d_ws, size_t ws_size,
                              hipStream_t stream) {
    const float* x = (const float*)d_in[0];
    float* out = (float*)d_out;
    float* norms = (float*)d_ws;                 // B*N floats
    float* rowsum = norms + BATCH * NTOK;        // B*N floats

    norms_kernel<<<(BATCH * NTOK) / 256, 256, 0, stream>>>(x, norms, rowsum);

    dim3 grid(NTOK / BN, NTOK / BM, BATCH);
    gemm_exp_kernel<<<grid, 256, 0, stream>>>(x, norms, out, rowsum);

    scale_kernel<<<2048, 256, 0, stream>>>(out, rowsum);
}

// Round 2
// 188.799 us; speedup vs baseline: 1.3474x; 1.3474x over previous
//
#include <hip/hip_runtime.h>
#include <hip/hip_bf16.h>

// x [B=4][C=256][N=4096] fp32 -> attention [B][N][N] fp32 (row softmax of cosine sim)
#define BATCH 4
#define CDIM  256
#define NTOK  4096

#define BM 64     // rows per block
#define BN 128    // cols per tile iteration

typedef short bf16x8 __attribute__((ext_vector_type(8)));
typedef float floatx4 __attribute__((ext_vector_type(4)));
typedef unsigned int uintx4 __attribute__((ext_vector_type(4)));
typedef unsigned int u32;

__device__ inline u32 f2bf1(float f) {
    u32 u = __float_as_uint(f);
    u += 0x7fffu + ((u >> 16) & 1u);   // RTNE
    return u >> 16;
}
__device__ inline u32 f2bf2(float lo, float hi) { return f2bf1(lo) | (f2bf1(hi) << 16); }

__device__ inline void gload_lds16(const short* g, short* l) {
    __builtin_amdgcn_global_load_lds(
        (const __attribute__((address_space(1))) u32*)g,
        (__attribute__((address_space(3))) u32*)l, 16, 0, 0);
}

// ---------- prep: x [B][C][N] f32 -> xn [B][N][C] bf16, rows normalized to unit L2 ----------
#define TT 32
__global__ __launch_bounds__(256) void prep_kernel(const float* __restrict__ x,
                                                   short* __restrict__ xn) {
    __shared__ float tile[TT][CDIM + 2];   // +2 pad: write banks (2*ti + c), 2-way free
    __shared__ float part[8][TT];
    __shared__ float rinv_s[TT];
    const int tid = threadIdx.x;
    const int blk = blockIdx.x;            // 0..511
    const int b = blk >> 7;                // 128 blocks per batch
    const int t0 = (blk & 127) * TT;
    const float* xb = x + (size_t)b * CDIM * NTOK;
    const int ti = tid & 31, cq = tid >> 5;   // cq 0..7
    float ss = 0.f;
    for (int c = cq; c < CDIM; c += 8) {
        float v = xb[(size_t)c * NTOK + t0 + ti];
        tile[ti][c] = v;
        ss += v * v;
    }
    part[cq][ti] = ss;
    __syncthreads();
    if (tid < TT) {
        float s = 0.f;
#pragma unroll
        for (int q = 0; q < 8; ++q) s += part[q][tid];
        rinv_s[tid] = 1.0f / sqrtf(s);
    }
    __syncthreads();
    const int tok = tid >> 3, seg = tid & 7;   // thread writes 32 channels of one token
    const float ri = rinv_s[tok];
    size_t obase = ((size_t)(b * NTOK + t0 + tok)) * CDIM + seg * 32;
#pragma unroll
    for (int j = 0; j < 4; ++j) {
        u32 w[4];
#pragma unroll
        for (int u = 0; u < 4; ++u) {
            float f0 = tile[tok][seg * 32 + j * 8 + 2 * u] * ri;
            float f1 = tile[tok][seg * 32 + j * 8 + 2 * u + 1] * ri;
            w[u] = f2bf2(f0, f1);
        }
        *(uintx4*)&xn[obase + j * 8] = (uintx4){w[0], w[1], w[2], w[3]};
    }
}

// ---------- fused two-sweep GEMM + softmax ----------
// Block: 64 rows x all 4096 cols, K=256. A in regs, B dbuf LDS chunks [128 tok][64 k].
// LDS B layout XOR-swizzled: 16B-chunk p of row tr holds logical chunk (p ^ (tr&7)).
__global__ __launch_bounds__(512, 2) void attn_kernel(const short* __restrict__ xn,
                                                      float* __restrict__ out) {
    __shared__ short Bs[2][128 * 64];       // 2 x 16 KB
    __shared__ float rowsumLds[BM][4];
    const int tid = threadIdx.x;
    const int b = blockIdx.y;
    const int rb = blockIdx.x * BM;
    const short* xnb = xn + (size_t)b * NTOK * CDIM;
    const int lane = tid & 63, wid = tid >> 6;     // 8 waves: 2 row x 4 col
    const int wr = (wid >> 2) * 32;                // 0 / 32
    const int wc = (wid & 3) * 32;                 // 0 / 32 / 64 / 96
    const int r0 = lane & 15, kq = lane >> 4;

    // staging roles: issue covers 64 token-rows; lane -> (token row, 16B chunk)
    const int trl = (wid << 3) + (lane >> 3);      // 0..63
    const int swz8 = (lane & 7) ^ (lane >> 3);     // inverse-swizzled source chunk

    // A fragments: rows rb+wr+m*16+r0, full K in registers (one-time L2 gather)
    bf16x8 afr[2][8];
#pragma unroll
    for (int m = 0; m < 2; ++m) {
        const short* arow = xnb + (size_t)(rb + wr + m * 16 + r0) * CDIM;
#pragma unroll
        for (int kc = 0; kc < 8; ++kc)
            afr[m][kc] = *(const bf16x8*)(arow + kc * 32 + kq * 8);
    }

    float psum[2][4] = {{0.f,0.f,0.f,0.f},{0.f,0.f,0.f,0.f}};
    float rinv[2][4];

    for (int sweep = 0; sweep < 2; ++sweep) {
        int cur = 0;
        {   // prologue: stage (ct=0, ck=0) into buf 0
            const short* s0 = xnb + (size_t)trl * CDIM + swz8 * 8;
            gload_lds16(s0, &Bs[0][wid << 9]);
            gload_lds16(s0 + 64 * CDIM, &Bs[0][4096 + (wid << 9)]);
        }
        __syncthreads();
        for (int ct = 0; ct < 32; ++ct) {
            floatx4 acc[2][2];
#pragma unroll
            for (int m = 0; m < 2; ++m)
#pragma unroll
                for (int n = 0; n < 2; ++n)
                    acc[m][n] = (floatx4){0.f, 0.f, 0.f, 0.f};

#pragma unroll
            for (int ck = 0; ck < 4; ++ck) {       // 64-k chunks
                int nck = ck + 1, nct = ct;
                if (nck == 4) { nck = 0; ++nct; }
                if (nct < 32) {                    // stage next chunk into other buf
                    const short* s0 = xnb + (size_t)(nct * BN + trl) * CDIM + nck * 64 + swz8 * 8;
                    short* d = &Bs[cur ^ 1][wid << 9];
                    gload_lds16(s0, d);
                    gload_lds16(s0 + 64 * CDIM, d + 4096);
                }
#pragma unroll
                for (int kk = 0; kk < 2; ++kk) {
                    bf16x8 bfr[2];
#pragma unroll
                    for (int n = 0; n < 2; ++n) {
                        int tr = wc + n * 16 + r0;
                        int j = (kk * 4 + kq) ^ (tr & 7);
                        bfr[n] = *(const bf16x8*)&Bs[cur][tr * 64 + j * 8];
                    }
                    acc[0][0] = __builtin_amdgcn_mfma_f32_16x16x32_bf16(afr[0][ck*2+kk], bfr[0], acc[0][0], 0,0,0);
                    acc[1][0] = __builtin_amdgcn_mfma_f32_16x16x32_bf16(afr[1][ck*2+kk], bfr[0], acc[1][0], 0,0,0);
                    acc[0][1] = __builtin_amdgcn_mfma_f32_16x16x32_bf16(afr[0][ck*2+kk], bfr[1], acc[0][1], 0,0,0);
                    acc[1][1] = __builtin_amdgcn_mfma_f32_16x16x32_bf16(afr[1][ck*2+kk], bfr[1], acc[1][1], 0,0,0);
                }
                __syncthreads();
                cur ^= 1;
            }

            if (sweep == 0) {
#pragma unroll
                for (int m = 0; m < 2; ++m)
#pragma unroll
                    for (int r = 0; r < 4; ++r)
                        psum[m][r] += __expf(acc[m][0][r] - 1.f) + __expf(acc[m][1][r] - 1.f);
            } else {
                float* outb = out + ((size_t)b << 24);
#pragma unroll
                for (int m = 0; m < 2; ++m)
#pragma unroll
                    for (int r = 0; r < 4; ++r) {
                        int row = rb + wr + m * 16 + kq * 4 + r;
                        float* p = outb + ((size_t)row << 12) + ct * BN + wc + r0;
                        p[0]  = __expf(acc[m][0][r] - 1.f) * rinv[m][r];
                        p[16] = __expf(acc[m][1][r] - 1.f) * rinv[m][r];
                    }
            }
        } // ct

        if (sweep == 0) {
            // reduce over the 16 r0-lanes sharing each row, combine 4 col-waves via LDS
#pragma unroll
            for (int m = 0; m < 2; ++m)
#pragma unroll
                for (int r = 0; r < 4; ++r) {
                    float v = psum[m][r];
                    v += __shfl_xor(v, 1);
                    v += __shfl_xor(v, 2);
                    v += __shfl_xor(v, 4);
                    v += __shfl_xor(v, 8);
                    psum[m][r] = v;
                }
            if (r0 == 0) {
#pragma unroll
                for (int m = 0; m < 2; ++m)
#pragma unroll
                    for (int r = 0; r < 4; ++r)
                        rowsumLds[wr + m * 16 + kq * 4 + r][wid & 3] = psum[m][r];
            }
            __syncthreads();
#pragma unroll
            for (int m = 0; m < 2; ++m)
#pragma unroll
                for (int r = 0; r < 4; ++r) {
                    int row = wr + m * 16 + kq * 4 + r;
                    rinv[m][r] = 1.0f / (rowsumLds[row][0] + rowsumLds[row][1] +
                                         rowsumLds[row][2] + rowsumLds[row][3]);
                }
        }
    } // sweep
}

extern "C" void kernel_launch(void* const* d_in, const int* in_sizes, int n_in,
                              void* d_out, int out_size, void* d_ws, size_t ws_size,
                              hipStream_t stream) {
    const float* x = (const float*)d_in[0];
    float* out = (float*)d_out;
    short* xn = (short*)d_ws;    // [B][N][C] bf16 = 8 MB

    prep_kernel<<<BATCH * (NTOK / TT), 256, 0, stream>>>(x, xn);

    dim3 grid(NTOK / BM, BATCH);
    attn_kernel<<<grid, 512, 0, stream>>>(xn, out);
}